// Round 17
// baseline (42.658 us; speedup 1.0000x reference)
//
#include <hip/hip_runtime.h>

// Chamfer loss: B=4, N=M=8192, D=3, fp32 in, scalar fp32 out.
// loss = mean_n min_m ||x_n-y_m||^2 + mean_m min_n ||...||^2 + lambda*bpp
//
// R16 = R15's verified K=8 math + R12's verified merge loop, with B
// delivery moved VMEM->LDS. Evidence: pass pinned ~30us across R6/R11/
// R12/R15 with VMEM B-load instruction count the only invariant
// (2048 dwordx4/CU ~= 35cy each; unique-byte dedup was NULL in R15).
// Fix: stage the 4096-pt B segment per block in 512-pt double-buffered
// LDS chunks via global_load_lds (width16, linear dest); each byte
// fetched ONCE per block (VMEM instrs/wave 128->16). Fragments read as
// ds_read_b64 pairs from lo/hi SPLIT PLANES (prep pre-splits records)
// so banks=(2r)%32 -> 2-way aliasing = free. DS ceiling ~12us/CU.
// Math (R15-verified, absmax 0.0): P = n2 - 2 a.y, one k-octet:
//   k0-5: -2a_d * (yhi_d | ylo_d)   k6: 1*n2hi   k7: 1*n2lo
// A lanes 0-31 real, lanes 32-63 ZERO (k8-15 dead -> B upper half free).
// C/D: col=lane&31, row=(q&3)+8*(q>>2)+4*(lane>>5).

typedef float  f16v __attribute__((ext_vector_type(16)));
typedef short  s8   __attribute__((ext_vector_type(8)));

#define NPTS    8192
#define NB      4
#define NPTOT   (NB * NPTS)       // 32768 points per cloud
#define NSEG    2                 // column-segment split (4096 cols each)
#define SEGPTS  4096
#define CHPTS   512               // chunk = 512 points = 16 tiles
#define NCHUNK  (SEGPTS / CHPTS)  // 8
#define RBLK    128

__device__ __forceinline__ ushort f2bf(float f) {
    uint u = __float_as_uint(f);
    u += 0x7FFF + ((u >> 16) & 1);          // round-to-nearest-even
    return (ushort)(u >> 16);
}
__device__ __forceinline__ float bf2f(ushort h) {
    return __uint_as_float(((uint)h) << 16);
}
__device__ __forceinline__ uint pk(ushort lo, ushort hi) {
    return (uint)lo | ((uint)hi << 16);
}

// prep: Arec (16B) + B lo/hi planes (8B each) per point, both clouds.
__global__ __launch_bounds__(256) void prep(
        const float* __restrict__ X, const float* __restrict__ Y,
        uint4* __restrict__ Arec, uint2* __restrict__ BLo,
        uint2* __restrict__ BHi) {
    int i = blockIdx.x * 256 + threadIdx.x;
    if (i >= 2 * NPTOT) return;
    const float* src = (i < NPTOT) ? X : Y;
    int p = i & (NPTOT - 1);
    float x0 = src[3*p], x1 = src[3*p+1], x2 = src[3*p+2];

    ushort a0 = f2bf(x0), a1 = f2bf(x1), a2 = f2bf(x2);
    float f0 = bf2f(a0), f1 = bf2f(a1), f2v = bf2f(a2);
    ushort m0 = f2bf(-2.0f * f0), m1 = f2bf(-2.0f * f1), m2 = f2bf(-2.0f * f2v);
    const ushort ONE = 0x3F80;
    Arec[i] = make_uint4(pk(m0, m1), pk(m2, m0), pk(m1, m2), pk(ONE, ONE));

    ushort l0 = f2bf(x0 - f0), l1 = f2bf(x1 - f1), l2 = f2bf(x2 - f2v);
    float n2 = __fmaf_rn(x0, x0, __fmaf_rn(x1, x1, x2 * x2));
    ushort nh = f2bf(n2);
    ushort nl = f2bf(n2 - bf2f(nh));
    BLo[i] = make_uint2(pk(a0, a1), pk(a2, l0));
    BHi[i] = make_uint2(pk(l1, l2), pk(nh, nl));
}

__device__ __forceinline__ s8 mkfrag(uint2 lo, uint2 hi) {
    uint4 u = make_uint4(lo.x, lo.y, hi.x, hi.y);
    return *(s8*)&u;
}

__global__ __launch_bounds__(256) void mfma_pass(
        const uint4* __restrict__ Arec, const uint2* __restrict__ BLo,
        const uint2* __restrict__ BHi, float* __restrict__ minsP) {
    // grid = 1024: pass(2) x batch(4) x rowblk(64) x seg(2)
    // block = 4 waves; wave owns 32 rows; block shares the B segment
    int bid  = blockIdx.x;
    int pass = bid >> 9;
    int r    = bid & 511;
    int b    = r >> 7;
    int rem  = r & 127;
    int blk  = rem >> 1;
    int seg  = rem & 1;
    int lane = threadIdx.x & 63;
    int wave = threadIdx.x >> 6;
    int ca   = pass;
    int cb   = 1 - pass;
    int ibase = (blk * 4 + wave) * 32;

    const s8 zf = {0, 0, 0, 0, 0, 0, 0, 0};

    // A fragment: lanes 0-31 real (row = lane&31), lanes 32-63 zero octet
    int pA = b * NPTS + ibase + (lane & 31);
    s8 afrag = (lane < 32)
        ? *(const s8*)&Arec[(size_t)ca * NPTOT + pA] : zf;

    size_t sbase = (size_t)cb * NPTOT + (size_t)b * NPTS + (size_t)seg * SEGPTS;

    __shared__ uint2 sLo[2][CHPTS];
    __shared__ uint2 sHi[2][CHPTS];

    // staging: wave w copies records [w*128, w*128+128) of the chunk;
    // each lane 16B (2 uint2) -> one global_load_lds width-16 per plane.
#define STAGE(c, buf)                                                        \
    {                                                                        \
        const uint2* gl = BLo + sbase + (size_t)(c) * CHPTS + wave * 128 + lane * 2; \
        const uint2* gh = BHi + sbase + (size_t)(c) * CHPTS + wave * 128 + lane * 2; \
        __builtin_amdgcn_global_load_lds(                                    \
            (const __attribute__((address_space(1))) void*)gl,               \
            (__attribute__((address_space(3))) void*)&sLo[buf][wave * 128],  \
            16, 0, 0);                                                       \
        __builtin_amdgcn_global_load_lds(                                    \
            (const __attribute__((address_space(1))) void*)gh,               \
            (__attribute__((address_space(3))) void*)&sHi[buf][wave * 128],  \
            16, 0, 0);                                                       \
    }

    const f16v zero16 = {0,0,0,0,0,0,0,0,0,0,0,0,0,0,0,0};
    f16v racc;
#pragma unroll
    for (int q = 0; q < 16; q++) racc[q] = 3.0e38f;

    int col = lane & 31;

    STAGE(0, 0);
    __syncthreads();

    for (int c = 0; c < NCHUNK; c++) {
        int buf = c & 1;
        if (c < NCHUNK - 1) STAGE(c + 1, (c + 1) & 1);
        // 16 tiles in this chunk, processed in pairs (R12 merge)
#pragma unroll
        for (int t = 0; t < 16; t += 2) {
            int r0 = t * 32 + col;
            s8 f0 = mkfrag(sLo[buf][r0], sHi[buf][r0]);
            s8 f1 = mkfrag(sLo[buf][r0 + 32], sHi[buf][r0 + 32]);
            f16v acc0 = __builtin_amdgcn_mfma_f32_32x32x16_bf16(
                afrag, f0, zero16, 0, 0, 0);
            f16v acc1 = __builtin_amdgcn_mfma_f32_32x32x16_bf16(
                afrag, f1, zero16, 0, 0, 0);
#pragma unroll
            for (int q = 0; q < 16; q++)
                racc[q] = fminf(fminf(acc0[q], acc1[q]), racc[q]);
        }
        __syncthreads();   // stage(c+1) landed; readers done with buf
    }

    // row-min across the 32 cols (lane bits 0-4), rows stay fixed
#pragma unroll
    for (int q = 0; q < 16; q++) {
        float v = racc[q];
        v = fminf(v, __shfl_xor(v, 1, 64));
        v = fminf(v, __shfl_xor(v, 2, 64));
        v = fminf(v, __shfl_xor(v, 4, 64));
        v = fminf(v, __shfl_xor(v, 8, 64));
        v = fminf(v, __shfl_xor(v, 16, 64));
        racc[q] = v;
    }
    if ((lane & 31) == 0) {
        float* dst = minsP + ((size_t)seg * 2 + pass) * NPTOT
                   + (size_t)b * NPTS + ibase;
        int half = lane >> 5;
#pragma unroll
        for (int q = 0; q < 16; q++)
            dst[(q & 3) + 8 * (q >> 2) + 4 * half] = racc[q];
    }
}

__global__ __launch_bounds__(256) void reduce1(
        const float* __restrict__ minsP,
        const float* __restrict__ X, const float* __restrict__ Y,
        float2* __restrict__ out2) {
    __shared__ float s1[256], s2[256];
    int t = threadIdx.x;
    int i = blockIdx.x * 256 + t;           // RBLK*256 == NPTOT exactly
    float mx = 3.0e38f, my = 3.0e38f;
#pragma unroll
    for (int s = 0; s < NSEG; s++) {
        mx = fminf(mx, minsP[((size_t)s * 2 + 0) * NPTOT + i]);
        my = fminf(my, minsP[((size_t)s * 2 + 1) * NPTOT + i]);
    }
    float a = bf2f(f2bf(X[3*i]));
    float bb = bf2f(f2bf(X[3*i+1]));
    float c = bf2f(f2bf(X[3*i+2]));
    float sx = mx + __fmaf_rn(a, a, __fmaf_rn(bb, bb, c * c));
    float d = bf2f(f2bf(Y[3*i]));
    float e = bf2f(f2bf(Y[3*i+1]));
    float f = bf2f(f2bf(Y[3*i+2]));
    float sy = my + __fmaf_rn(d, d, __fmaf_rn(e, e, f * f));
    s1[t] = sx; s2[t] = sy;
    __syncthreads();
    for (int s = 128; s > 0; s >>= 1) {
        if (t < s) { s1[t] += s1[t + s]; s2[t] += s2[t + s]; }
        __syncthreads();
    }
    if (t == 0) out2[blockIdx.x] = make_float2(s1[0], s2[0]);
}

__global__ __launch_bounds__(RBLK) void reduce2(
        const float2* __restrict__ p2,
        const float* __restrict__ bpp, const float* __restrict__ lam,
        float* __restrict__ out) {
    __shared__ float s[RBLK];
    int t = threadIdx.x;
    float2 p = p2[t];
    s[t] = p.x + p.y;
    __syncthreads();
    for (int h = RBLK / 2; h > 0; h >>= 1) {
        if (t < h) s[t] += s[t + h];
        __syncthreads();
    }
    if (t == 0) out[0] = s[0] * (1.0f / (float)NPTOT) + lam[0] * bpp[0];
}

extern "C" void kernel_launch(void* const* d_in, const int* in_sizes, int n_in,
                              void* d_out, int out_size, void* d_ws, size_t ws_size,
                              hipStream_t stream) {
    const float* X   = (const float*)d_in[0];   // pc_pred  [4,8192,3]
    const float* Y   = (const float*)d_in[1];   // pc_target[4,8192,3]
    const float* bpp = (const float*)d_in[2];
    const float* lam = (const float*)d_in[3];
    float* out = (float*)d_out;

    char* w = (char*)d_ws;
    float2* p2    = (float2*)w;                 w += 1024;
    float*  minsP = (float*)w;                  w += (size_t)NSEG * 2 * NPTOT * sizeof(float);
    uint4*  Arec  = (uint4*)w;                  w += (size_t)2 * NPTOT * sizeof(uint4);
    uint2*  BLo   = (uint2*)w;                  w += (size_t)2 * NPTOT * sizeof(uint2);
    uint2*  BHi   = (uint2*)w;

    prep<<<(2 * NPTOT + 255) / 256, 256, 0, stream>>>(X, Y, Arec, BLo, BHi);
    mfma_pass<<<1024, 256, 0, stream>>>(Arec, BLo, BHi, minsP);
    reduce1<<<RBLK, 256, 0, stream>>>(minsP, X, Y, p2);
    reduce2<<<1, RBLK, 0, stream>>>(p2, bpp, lam, out);
}